// Round 16
// baseline (94.700 us; speedup 1.0000x reference)
//
#include <hip/hip_runtime.h>
#include <math.h>

#define NSEQ   2048
#define DMODEL 1024
#define NHEADS 16
#define HD     64

typedef short bf16x8 __attribute__((ext_vector_type(8)));
typedef float f32x4  __attribute__((ext_vector_type(4)));
typedef unsigned short ushort8_t __attribute__((ext_vector_type(8)));

// RTNE float -> bf16 bits
__device__ __forceinline__ unsigned short f2bf(float x) {
    unsigned int u = __builtin_bit_cast(unsigned int, x);
    unsigned int r = (u + 0x7FFFu + ((u >> 16) & 1u)) >> 16;
    return (unsigned short)r;
}

// ---------------------------------------------------------------------------
// Convert inputs to bf16: x(2M)->xb, Wq/Wk/Wv(3x1M)->Wb[3072][1024], Wo->Wob.
// ---------------------------------------------------------------------------
__global__ __launch_bounds__(256) void convert_inputs(
    const float* __restrict__ x,  const float* __restrict__ Wq,
    const float* __restrict__ Wk, const float* __restrict__ Wv,
    const float* __restrict__ Wo,
    unsigned short* __restrict__ xb, unsigned short* __restrict__ Wb,
    unsigned short* __restrict__ Wob)
{
    const size_t i8 = ((size_t)blockIdx.x * 256 + threadIdx.x) * 8;
    const float* src;
    unsigned short* dst;
    if (i8 < (2ull << 20)) {
        src = x + i8;  dst = xb + i8;
    } else if (i8 < (5ull << 20)) {
        const size_t o = i8 - (2ull << 20);
        const size_t s = o >> 20;
        src = (s == 0 ? Wq : (s == 1 ? Wk : Wv)) + (o & ((1u << 20) - 1));
        dst = Wb + o;
    } else {
        const size_t o = i8 - (5ull << 20);
        src = Wo + o;  dst = Wob + o;
    }
    const float4 v0 = *reinterpret_cast<const float4*>(src);
    const float4 v1 = *reinterpret_cast<const float4*>(src + 4);
    ushort8_t r;
    r[0] = f2bf(v0.x); r[1] = f2bf(v0.y); r[2] = f2bf(v0.z); r[3] = f2bf(v0.w);
    r[4] = f2bf(v1.x); r[5] = f2bf(v1.y); r[6] = f2bf(v1.z); r[7] = f2bf(v1.w);
    *reinterpret_cast<ushort8_t*>(dst) = r;
}

// ---------------------------------------------------------------------------
// bf16 MFMA GEMM (B-transposed), BM=128 x BN=64, BK=64; 4 waves stacked in M.
// T14 async-STAGE prefetch (R12-verified). Swizzled-LDS (R7 family).
// QKV=1: cols 0-1023 (Q): bf16 out + qnc2 float2{qn, 2/(1-qn)};
//        cols 1024-2047 (K): bf16 out + knck float2{kn, 1/(1-kn)};
//        cols 2048-3071 (V): bf16 out TRANSPOSED directly into Vt[dm][n].
// QKV=0: plain f32 output C0 (N=1024).
// ---------------------------------------------------------------------------
template <int QKV>
__global__ __launch_bounds__(256) void gemm_bt_bf16(
    const unsigned short* __restrict__ A, const unsigned short* __restrict__ B,
    float* __restrict__ C0,
    unsigned short* __restrict__ QbO, float2* __restrict__ qnc2O,
    unsigned short* __restrict__ KbO, float2* __restrict__ knckO,
    unsigned short* __restrict__ VtO)
{
    __shared__ unsigned short Ahs[128 * 64];
    __shared__ unsigned short Bhs[64 * 64];

    const int bm   = blockIdx.x * 128;
    const int bn   = blockIdx.y * 64;
    const int t    = threadIdx.x;
    const int wid  = t >> 6;
    const int lane = t & 63;
    const int g    = lane >> 4;
    const int r    = lane & 15;
    const int wm   = wid * 32;           // wave tile 32(M) x 64(N)

    const int sel = QKV ? (bn >> 10) : 0;
    const int bnl = QKV ? (bn & 1023) : bn;

    f32x4 acc[2][4];
#pragma unroll
    for (int i = 0; i < 2; ++i)
#pragma unroll
        for (int j = 0; j < 4; ++j) acc[i][j] = (f32x4){0.f, 0.f, 0.f, 0.f};

    const int srowA = t >> 1;        // 0..127
    const int shalA = t & 1;         // k-half
    const int srowB = t >> 2;        // 0..63
    const int squadB = t & 3;

    const unsigned short* Ag = &A[(size_t)(bm + srowA) * DMODEL + shalA * 32];
    const unsigned short* Bg = &B[(size_t)(bn + srowB) * DMODEL + squadB * 16];

    ushort8_t av[4], bv[2];
#pragma unroll
    for (int c = 0; c < 4; ++c)
        av[c] = *reinterpret_cast<const ushort8_t*>(Ag + c * 8);
#pragma unroll
    for (int c = 0; c < 2; ++c)
        bv[c] = *reinterpret_cast<const ushort8_t*>(Bg + c * 8);

    for (int k0 = 0; k0 < DMODEL; k0 += 64) {
        __syncthreads();
#pragma unroll
        for (int c = 0; c < 4; ++c) {
            const int sw = ((shalA * 4 + c) ^ (srowA & 7)) * 8;
            *reinterpret_cast<ushort8_t*>(&Ahs[srowA * 64 + sw]) = av[c];
        }
#pragma unroll
        for (int c = 0; c < 2; ++c) {
            const int sw = ((squadB * 2 + c) ^ (srowB & 7)) * 8;
            *reinterpret_cast<ushort8_t*>(&Bhs[srowB * 64 + sw]) = bv[c];
        }
        if (k0 + 64 < DMODEL) {   // issue next-tile loads (overlap with MFMAs)
#pragma unroll
            for (int c = 0; c < 4; ++c)
                av[c] = *reinterpret_cast<const ushort8_t*>(
                    Ag + k0 + 64 + c * 8);
#pragma unroll
            for (int c = 0; c < 2; ++c)
                bv[c] = *reinterpret_cast<const ushort8_t*>(
                    Bg + k0 + 64 + c * 8);
        }
        __syncthreads();

#pragma unroll
        for (int dc = 0; dc < 2; ++dc) {
            bf16x8 af[2], bfr[4];
#pragma unroll
            for (int mt = 0; mt < 2; ++mt)
                af[mt] = *reinterpret_cast<const bf16x8*>(
                    &Ahs[(wm + mt * 16 + r) * 64 + ((dc * 4 + g) ^ (r & 7)) * 8]);
#pragma unroll
            for (int nt = 0; nt < 4; ++nt)
                bfr[nt] = *reinterpret_cast<const bf16x8*>(
                    &Bhs[(nt * 16 + r) * 64 + ((dc * 4 + g) ^ (r & 7)) * 8]);
#pragma unroll
            for (int mt = 0; mt < 2; ++mt)
#pragma unroll
                for (int nt = 0; nt < 4; ++nt)
                    acc[mt][nt] = __builtin_amdgcn_mfma_f32_16x16x32_bf16(
                        af[mt], bfr[nt], acc[mt][nt], 0, 0, 0);
        }
    }

    if (QKV) {
        if (sel < 2) {
            unsigned short* Hb = sel ? KbO : QbO;
            float2* dst2 = sel ? knckO : qnc2O;
            const int hh = bnl >> 6;   // one head per block (64 cols)
#pragma unroll
            for (int mt = 0; mt < 2; ++mt) {
#pragma unroll
                for (int rg = 0; rg < 4; ++rg) {
                    float ss = 0.f;
#pragma unroll
                    for (int nt = 0; nt < 4; ++nt) {
                        const float v = acc[mt][nt][rg];
                        ss = fmaf(v, v, ss);
                        Hb[(size_t)(bm + wm + mt * 16 + g * 4 + rg) * 1024 +
                           bnl + nt * 16 + r] = f2bf(v);
                    }
                    ss += __shfl_xor(ss, 1, 64);
                    ss += __shfl_xor(ss, 2, 64);
                    ss += __shfl_xor(ss, 4, 64);
                    ss += __shfl_xor(ss, 8, 64);
                    if (r == 0) {
                        const int row = bm + wm + mt * 16 + g * 4 + rg;
                        dst2[hh * NSEQ + row] =
                            make_float2(ss, (sel ? 1.0f : 2.0f) / (1.0f - ss));
                    }
                }
            }
        } else {
            // V: write transposed bf16 directly (Vt[(h*64+d)][n])
#pragma unroll
            for (int mt = 0; mt < 2; ++mt)
#pragma unroll
                for (int nt = 0; nt < 4; ++nt) {
                    ushort4 o4;
                    o4.x = f2bf(acc[mt][nt][0]);
                    o4.y = f2bf(acc[mt][nt][1]);
                    o4.z = f2bf(acc[mt][nt][2]);
                    o4.w = f2bf(acc[mt][nt][3]);
                    *reinterpret_cast<ushort4*>(
                        &VtO[(size_t)(bnl + nt * 16 + r) * NSEQ +
                             bm + wm + mt * 16 + g * 4]) = o4;
                }
        }
    } else {
#pragma unroll
        for (int mt = 0; mt < 2; ++mt)
#pragma unroll
            for (int nt = 0; nt < 4; ++nt)
#pragma unroll
                for (int rg = 0; rg < 4; ++rg)
                    C0[(size_t)(bm + wm + mt * 16 + g * 4 + rg) * 1024 +
                       bnl + nt * 16 + r] = acc[mt][nt][rg];
    }
}

// ---------------------------------------------------------------------------
// MFMA hyperbolic attention v9 = v8 core (measured layouts, T14 prefetch)
// with NJH=1: full j-span per block, l fully reduced in-kernel, so the
// epilogue normalizes in-register and writes FINAL bf16 Ob directly.
// Opart/lpart/merge_kernel eliminated (~20MB HBM traffic + a launch).
// Grid (NSEQ/64, NHEADS). 4 waves; wave w: q rows [n0+16w,+16).
// ---------------------------------------------------------------------------
__global__ __launch_bounds__(256) void hyp_attn_v9(
    const unsigned short* __restrict__ Qb, const unsigned short* __restrict__ Kb,
    const unsigned short* __restrict__ Vt,
    const float2* __restrict__ qnc2_a, const float2* __restrict__ knck_a,
    unsigned short* __restrict__ Ob)
{
    __shared__ unsigned short Khs[64 * 64];   // [j][k-seg swz]
    __shared__ unsigned short Vts[64 * 64];   // [d][j-seg swz]
    __shared__ unsigned short Ps[4][16 * 64]; // per-wave [q][j-seg swz]
    __shared__ float2 kcs[NSEQ];              // {kn, ck} per j (16KB)

    const int h    = blockIdx.y;
    const int n0   = blockIdx.x * 64;
    const int t    = threadIdx.x;
    const int wid  = t >> 6;
    const int lane = t & 63;
    const int g    = lane >> 4;
    const int r    = lane & 15;
    const int qb   = n0 + wid * 16;

    // ---- prologue: Q frags, per-q constants, kn/ck span -> LDS ----
    bf16x8 qf[2];
#pragma unroll
    for (int dc = 0; dc < 2; ++dc)
        qf[dc] = *reinterpret_cast<const bf16x8*>(
            Qb + (size_t)(qb + r) * DMODEL + h * HD + dc * 32 + g * 8);

    float qn_r[4], c2q[4];
#pragma unroll
    for (int rg = 0; rg < 4; ++rg) {
        const float2 qv = qnc2_a[h * NSEQ + qb + g * 4 + rg];
        qn_r[rg] = qv.x;
        c2q[rg]  = qv.y;
    }
#pragma unroll
    for (int i = 0; i < NSEQ / 256; ++i)
        kcs[i * 256 + t] = knck_a[h * NSEQ + i * 256 + t];

    f32x4 oacc[4];
#pragma unroll
    for (int nt = 0; nt < 4; ++nt) oacc[nt] = (f32x4){0.f, 0.f, 0.f, 0.f};
    float l_acc[4] = {0.f, 0.f, 0.f, 0.f};

    const int srow = t >> 2;
    const int c0   = (t & 3) * 2;
    const int sw0  = (c0 ^ (srow & 7)) * 8;
    const int sw1  = ((c0 + 1) ^ (srow & 7)) * 8;
    const int sg   = (t & 3) * 16;
    unsigned short* Pw = &Ps[wid][0];

    const unsigned short* Kg = Kb + (size_t)srow * DMODEL + h * HD + sg;
    const unsigned short* Vg = Vt + (size_t)(h * HD + srow) * NSEQ + sg;

    // prefetch tile 0 into regs
    ushort8_t kr0 = *reinterpret_cast<const ushort8_t*>(Kg);
    ushort8_t kr1 = *reinterpret_cast<const ushort8_t*>(Kg + 8);
    ushort8_t vr0 = *reinterpret_cast<const ushort8_t*>(Vg);
    ushort8_t vr1 = *reinterpret_cast<const ushort8_t*>(Vg + 8);

    const int ntb = NSEQ / 64;
    for (int tb = 0; tb < ntb; ++tb) {
        __syncthreads();   // prev tile consumed; (tb=0) kcs visible
        *reinterpret_cast<ushort8_t*>(&Khs[srow * 64 + sw0]) = kr0;
        *reinterpret_cast<ushort8_t*>(&Khs[srow * 64 + sw1]) = kr1;
        *reinterpret_cast<ushort8_t*>(&Vts[srow * 64 + sw0]) = vr0;
        *reinterpret_cast<ushort8_t*>(&Vts[srow * 64 + sw1]) = vr1;
        if (tb + 1 < ntb) {   // T14: next-tile loads overlap with compute
            const unsigned short* kn_ = Kg + (size_t)(tb + 1) * 64 * DMODEL;
            const unsigned short* vn_ = Vg + (tb + 1) * 64;
            kr0 = *reinterpret_cast<const ushort8_t*>(kn_);
            kr1 = *reinterpret_cast<const ushort8_t*>(kn_ + 8);
            vr0 = *reinterpret_cast<const ushort8_t*>(vn_);
            vr1 = *reinterpret_cast<const ushort8_t*>(vn_ + 8);
        }
        __syncthreads();

        // ---- S tiles + distance -> w -> P (swizzled wave-private LDS) ----
#pragma unroll
        for (int jt = 0; jt < 4; ++jt) {
            f32x4 sac = (f32x4){0.f, 0.f, 0.f, 0.f};
#pragma unroll
            for (int dc = 0; dc < 2; ++dc) {
                const bf16x8 kb = *reinterpret_cast<const bf16x8*>(
                    &Khs[(jt * 16 + r) * 64 + ((dc * 4 + g) ^ (r & 7)) * 8]);
                sac = __builtin_amdgcn_mfma_f32_16x16x32_bf16(qf[dc], kb, sac, 0, 0, 0);
            }
            const float2 kc = kcs[tb * 64 + jt * 16 + r];
#pragma unroll
            for (int rg = 0; rg < 4; ++rg) {
                const float dsq = fmaf(-2.f, sac[rg], qn_r[rg] + kc.x);
                const float ca  = fmaxf(fmaf(dsq, c2q[rg] * kc.y, 1.f), 1.0f);
                const float s2  = fmaf(ca, ca, -1.f);
                const float wj  = ca - __builtin_amdgcn_sqrtf(s2);
                l_acc[rg] += wj;
                const int qrow = g * 4 + rg;
                Pw[qrow * 64 +
                   ((2 * jt + (r >> 3)) ^ (qrow & 7)) * 8 + (r & 7)] = f2bf(wj);
            }
        }
        // Pw is wave-private: within-wave ds ordering suffices

        // ---- PV: O[q][d] += P . V ----
#pragma unroll
        for (int kc2 = 0; kc2 < 2; ++kc2) {
            const bf16x8 pa = *reinterpret_cast<const bf16x8*>(
                &Pw[r * 64 + ((kc2 * 4 + g) ^ (r & 7)) * 8]);
#pragma unroll
            for (int nt = 0; nt < 4; ++nt) {
                const bf16x8 vb = *reinterpret_cast<const bf16x8*>(
                    &Vts[(nt * 16 + r) * 64 + ((kc2 * 4 + g) ^ (r & 7)) * 8]);
                oacc[nt] = __builtin_amdgcn_mfma_f32_16x16x32_bf16(pa, vb, oacc[nt], 0, 0, 0);
            }
        }
    }

    // ---- l reduce over the 16 r-lanes (full denominator) ----
#pragma unroll
    for (int rg = 0; rg < 4; ++rg) {
        l_acc[rg] += __shfl_xor(l_acc[rg], 1, 64);
        l_acc[rg] += __shfl_xor(l_acc[rg], 2, 64);
        l_acc[rg] += __shfl_xor(l_acc[rg], 4, 64);
        l_acc[rg] += __shfl_xor(l_acc[rg], 8, 64);
    }

    // ---- epilogue: normalize in-register, write FINAL bf16 Ob ----
#pragma unroll
    for (int rg = 0; rg < 4; ++rg) {
        const float inv = 1.0f / l_acc[rg];
        unsigned short* dst =
            Ob + (size_t)(qb + g * 4 + rg) * DMODEL + h * HD + r;
#pragma unroll
        for (int nt = 0; nt < 4; ++nt)
            dst[nt * 16] = f2bf(oacc[nt][rg] * inv);
    }
}

// ---------------------------------------------------------------------------
extern "C" void kernel_launch(void* const* d_in, const int* in_sizes, int n_in,
                              void* d_out, int out_size, void* d_ws, size_t ws_size,
                              hipStream_t stream)
{
    const float* x  = (const float*)d_in[0];
    const float* Wq = (const float*)d_in[1];
    const float* Wk = (const float*)d_in[2];
    const float* Wv = (const float*)d_in[3];
    const float* Wo = (const float*)d_in[4];
    float* out = (float*)d_out;

    char* ws = (char*)d_ws;
    const size_t MB = 1048576;
    unsigned short* xb   = (unsigned short*)(ws);             // 4MB (-> Ob)
    unsigned short* Wb   = (unsigned short*)(ws + 4  * MB);   // 6MB
    unsigned short* Wob  = (unsigned short*)(ws + 10 * MB);   // 2MB
    unsigned short* Qbuf = (unsigned short*)(ws + 12 * MB);   // 4MB
    unsigned short* Kbuf = (unsigned short*)(ws + 16 * MB);   // 4MB
    unsigned short* Vt   = (unsigned short*)(ws + 20 * MB);   // 4MB
    float2*         qnc2 = (float2*)(ws + 24 * MB);           // 256KB
    float2*         knck = (float2*)(ws + 24 * MB + 262144);  // 256KB
    unsigned short* Ob   = xb;   // xb dead after QKV GEMM

    const dim3 blk(256);

    // 1. fp32 -> bf16 conversions
    convert_inputs<<<3072, blk, 0, stream>>>(x, Wq, Wk, Wv, Wo, xb, Wb, Wob);

    // 2. fused QKV projection + norms + V-transpose in epilogue  [768 blocks]
    gemm_bt_bf16<1><<<dim3(NSEQ / 128, 3072 / 64), blk, 0, stream>>>(
        xb, Wb, nullptr, Qbuf, qnc2, Kbuf, knck, Vt);

    // 3. fused attention -> final bf16 Ob (no j-split, no merge)  [512 blocks]
    hyp_attn_v9<<<dim3(NSEQ / 64, NHEADS), blk, 0, stream>>>(
        Qbuf, Kbuf, Vt, qnc2, knck, Ob);

    // 4. output projection  [256 blocks]
    gemm_bt_bf16<0><<<dim3(NSEQ / 128, DMODEL / 64), blk, 0, stream>>>(
        Ob, Wob, out, nullptr, nullptr, nullptr, nullptr, nullptr);
}

// Round 17
// 92.049 us; speedup vs baseline: 1.0288x; 1.0288x over previous
//
#include <hip/hip_runtime.h>
#include <math.h>

#define NSEQ   2048
#define DMODEL 1024
#define NHEADS 16
#define HD     64
#define NJH    2
#define JSPAN  (NSEQ / NJH)

typedef short bf16x8 __attribute__((ext_vector_type(8)));
typedef float f32x4  __attribute__((ext_vector_type(4)));
typedef unsigned short ushort8_t __attribute__((ext_vector_type(8)));

// RTNE float -> bf16 bits
__device__ __forceinline__ unsigned short f2bf(float x) {
    unsigned int u = __builtin_bit_cast(unsigned int, x);
    unsigned int r = (u + 0x7FFFu + ((u >> 16) & 1u)) >> 16;
    return (unsigned short)r;
}

// ---------------------------------------------------------------------------
// Convert inputs to bf16: x(2M)->xb, Wq/Wk/Wv(3x1M)->Wb[3072][1024], Wo->Wob.
// ---------------------------------------------------------------------------
__global__ __launch_bounds__(256) void convert_inputs(
    const float* __restrict__ x,  const float* __restrict__ Wq,
    const float* __restrict__ Wk, const float* __restrict__ Wv,
    const float* __restrict__ Wo,
    unsigned short* __restrict__ xb, unsigned short* __restrict__ Wb,
    unsigned short* __restrict__ Wob)
{
    const size_t i8 = ((size_t)blockIdx.x * 256 + threadIdx.x) * 8;
    const float* src;
    unsigned short* dst;
    if (i8 < (2ull << 20)) {
        src = x + i8;  dst = xb + i8;
    } else if (i8 < (5ull << 20)) {
        const size_t o = i8 - (2ull << 20);
        const size_t s = o >> 20;
        src = (s == 0 ? Wq : (s == 1 ? Wk : Wv)) + (o & ((1u << 20) - 1));
        dst = Wb + o;
    } else {
        const size_t o = i8 - (5ull << 20);
        src = Wo + o;  dst = Wob + o;
    }
    const float4 v0 = *reinterpret_cast<const float4*>(src);
    const float4 v1 = *reinterpret_cast<const float4*>(src + 4);
    ushort8_t r;
    r[0] = f2bf(v0.x); r[1] = f2bf(v0.y); r[2] = f2bf(v0.z); r[3] = f2bf(v0.w);
    r[4] = f2bf(v1.x); r[5] = f2bf(v1.y); r[6] = f2bf(v1.z); r[7] = f2bf(v1.w);
    *reinterpret_cast<ushort8_t*>(dst) = r;
}

// ---------------------------------------------------------------------------
// bf16 MFMA GEMM (B-transposed), BM=128 x BN=64, BK=64; 4 waves stacked in M.
// T14 async-STAGE prefetch (R12-verified). Swizzled-LDS (R7 family).
// QKV=1: cols 0-1023 (Q): bf16 out + qnc2 float2{qn, 2/(1-qn)};
//        cols 1024-2047 (K): bf16 out + knck float2{kn, 1/(1-kn)};
//        cols 2048-3071 (V): bf16 out TRANSPOSED directly into Vt[dm][n].
// QKV=0: plain f32 output C0 (N=1024).
// ---------------------------------------------------------------------------
template <int QKV>
__global__ __launch_bounds__(256) void gemm_bt_bf16(
    const unsigned short* __restrict__ A, const unsigned short* __restrict__ B,
    float* __restrict__ C0,
    unsigned short* __restrict__ QbO, float2* __restrict__ qnc2O,
    unsigned short* __restrict__ KbO, float2* __restrict__ knckO,
    unsigned short* __restrict__ VtO)
{
    __shared__ unsigned short Ahs[128 * 64];
    __shared__ unsigned short Bhs[64 * 64];

    const int bm   = blockIdx.x * 128;
    const int bn   = blockIdx.y * 64;
    const int t    = threadIdx.x;
    const int wid  = t >> 6;
    const int lane = t & 63;
    const int g    = lane >> 4;
    const int r    = lane & 15;
    const int wm   = wid * 32;           // wave tile 32(M) x 64(N)

    const int sel = QKV ? (bn >> 10) : 0;
    const int bnl = QKV ? (bn & 1023) : bn;

    f32x4 acc[2][4];
#pragma unroll
    for (int i = 0; i < 2; ++i)
#pragma unroll
        for (int j = 0; j < 4; ++j) acc[i][j] = (f32x4){0.f, 0.f, 0.f, 0.f};

    const int srowA = t >> 1;        // 0..127
    const int shalA = t & 1;         // k-half
    const int srowB = t >> 2;        // 0..63
    const int squadB = t & 3;

    const unsigned short* Ag = &A[(size_t)(bm + srowA) * DMODEL + shalA * 32];
    const unsigned short* Bg = &B[(size_t)(bn + srowB) * DMODEL + squadB * 16];

    ushort8_t av[4], bv[2];
#pragma unroll
    for (int c = 0; c < 4; ++c)
        av[c] = *reinterpret_cast<const ushort8_t*>(Ag + c * 8);
#pragma unroll
    for (int c = 0; c < 2; ++c)
        bv[c] = *reinterpret_cast<const ushort8_t*>(Bg + c * 8);

    for (int k0 = 0; k0 < DMODEL; k0 += 64) {
        __syncthreads();
#pragma unroll
        for (int c = 0; c < 4; ++c) {
            const int sw = ((shalA * 4 + c) ^ (srowA & 7)) * 8;
            *reinterpret_cast<ushort8_t*>(&Ahs[srowA * 64 + sw]) = av[c];
        }
#pragma unroll
        for (int c = 0; c < 2; ++c) {
            const int sw = ((squadB * 2 + c) ^ (srowB & 7)) * 8;
            *reinterpret_cast<ushort8_t*>(&Bhs[srowB * 64 + sw]) = bv[c];
        }
        if (k0 + 64 < DMODEL) {   // issue next-tile loads (overlap with MFMAs)
#pragma unroll
            for (int c = 0; c < 4; ++c)
                av[c] = *reinterpret_cast<const ushort8_t*>(
                    Ag + k0 + 64 + c * 8);
#pragma unroll
            for (int c = 0; c < 2; ++c)
                bv[c] = *reinterpret_cast<const ushort8_t*>(
                    Bg + k0 + 64 + c * 8);
        }
        __syncthreads();

#pragma unroll
        for (int dc = 0; dc < 2; ++dc) {
            bf16x8 af[2], bfr[4];
#pragma unroll
            for (int mt = 0; mt < 2; ++mt)
                af[mt] = *reinterpret_cast<const bf16x8*>(
                    &Ahs[(wm + mt * 16 + r) * 64 + ((dc * 4 + g) ^ (r & 7)) * 8]);
#pragma unroll
            for (int nt = 0; nt < 4; ++nt)
                bfr[nt] = *reinterpret_cast<const bf16x8*>(
                    &Bhs[(nt * 16 + r) * 64 + ((dc * 4 + g) ^ (r & 7)) * 8]);
#pragma unroll
            for (int mt = 0; mt < 2; ++mt)
#pragma unroll
                for (int nt = 0; nt < 4; ++nt)
                    acc[mt][nt] = __builtin_amdgcn_mfma_f32_16x16x32_bf16(
                        af[mt], bfr[nt], acc[mt][nt], 0, 0, 0);
        }
    }

    if (QKV) {
        if (sel < 2) {
            unsigned short* Hb = sel ? KbO : QbO;
            float2* dst2 = sel ? knckO : qnc2O;
            const int hh = bnl >> 6;   // one head per block (64 cols)
#pragma unroll
            for (int mt = 0; mt < 2; ++mt) {
#pragma unroll
                for (int rg = 0; rg < 4; ++rg) {
                    float ss = 0.f;
#pragma unroll
                    for (int nt = 0; nt < 4; ++nt) {
                        const float v = acc[mt][nt][rg];
                        ss = fmaf(v, v, ss);
                        Hb[(size_t)(bm + wm + mt * 16 + g * 4 + rg) * 1024 +
                           bnl + nt * 16 + r] = f2bf(v);
                    }
                    ss += __shfl_xor(ss, 1, 64);
                    ss += __shfl_xor(ss, 2, 64);
                    ss += __shfl_xor(ss, 4, 64);
                    ss += __shfl_xor(ss, 8, 64);
                    if (r == 0) {
                        const int row = bm + wm + mt * 16 + g * 4 + rg;
                        dst2[hh * NSEQ + row] =
                            make_float2(ss, (sel ? 1.0f : 2.0f) / (1.0f - ss));
                    }
                }
            }
        } else {
            // V: write transposed bf16 directly (Vt[(h*64+d)][n])
#pragma unroll
            for (int mt = 0; mt < 2; ++mt)
#pragma unroll
                for (int nt = 0; nt < 4; ++nt) {
                    ushort4 o4;
                    o4.x = f2bf(acc[mt][nt][0]);
                    o4.y = f2bf(acc[mt][nt][1]);
                    o4.z = f2bf(acc[mt][nt][2]);
                    o4.w = f2bf(acc[mt][nt][3]);
                    *reinterpret_cast<ushort4*>(
                        &VtO[(size_t)(bnl + nt * 16 + r) * NSEQ +
                             bm + wm + mt * 16 + g * 4]) = o4;
                }
        }
    } else {
#pragma unroll
        for (int mt = 0; mt < 2; ++mt)
#pragma unroll
            for (int nt = 0; nt < 4; ++nt)
#pragma unroll
                for (int rg = 0; rg < 4; ++rg)
                    C0[(size_t)(bm + wm + mt * 16 + g * 4 + rg) * 1024 +
                       bnl + nt * 16 + r] = acc[mt][nt][rg];
    }
}

// ---------------------------------------------------------------------------
// MFMA hyperbolic attention v8 (R15-measured 52.5us): v5 core layouts,
// T14 prefetch, kn/ck packed float2, j-split x2.
// Grid (NSEQ/64, NHEADS, NJH). 4 waves; wave w: q rows [n0+16w,+16).
// ---------------------------------------------------------------------------
__global__ __launch_bounds__(256) void hyp_attn_v8(
    const unsigned short* __restrict__ Qb, const unsigned short* __restrict__ Kb,
    const unsigned short* __restrict__ Vt,
    const float2* __restrict__ qnc2_a, const float2* __restrict__ knck_a,
    float* __restrict__ Opart, float* __restrict__ lpart)
{
    __shared__ unsigned short Khs[64 * 64];   // [j][k-seg swz]
    __shared__ unsigned short Vts[64 * 64];   // [d][j-seg swz]
    __shared__ unsigned short Ps[4][16 * 64]; // per-wave [q][j-seg swz]
    __shared__ float2 kcs[JSPAN];             // {kn, ck} per j

    const int h    = blockIdx.y;
    const int n0   = blockIdx.x * 64;
    const int jh   = blockIdx.z;
    const int t    = threadIdx.x;
    const int wid  = t >> 6;
    const int lane = t & 63;
    const int g    = lane >> 4;
    const int r    = lane & 15;
    const int qb   = n0 + wid * 16;

    // ---- prologue: Q frags, per-q constants, kn/ck span -> LDS ----
    bf16x8 qf[2];
#pragma unroll
    for (int dc = 0; dc < 2; ++dc)
        qf[dc] = *reinterpret_cast<const bf16x8*>(
            Qb + (size_t)(qb + r) * DMODEL + h * HD + dc * 32 + g * 8);

    float qn_r[4], c2q[4];
#pragma unroll
    for (int rg = 0; rg < 4; ++rg) {
        const float2 qv = qnc2_a[h * NSEQ + qb + g * 4 + rg];
        qn_r[rg] = qv.x;
        c2q[rg]  = qv.y;
    }
#pragma unroll
    for (int i = 0; i < JSPAN / 256; ++i)
        kcs[i * 256 + t] = knck_a[h * NSEQ + jh * JSPAN + i * 256 + t];

    f32x4 oacc[4];
#pragma unroll
    for (int nt = 0; nt < 4; ++nt) oacc[nt] = (f32x4){0.f, 0.f, 0.f, 0.f};
    float l_acc[4] = {0.f, 0.f, 0.f, 0.f};

    const int srow = t >> 2;
    const int c0   = (t & 3) * 2;
    const int sw0  = (c0 ^ (srow & 7)) * 8;
    const int sw1  = ((c0 + 1) ^ (srow & 7)) * 8;
    const int sg   = (t & 3) * 16;
    unsigned short* Pw = &Ps[wid][0];

    const unsigned short* Kg = Kb + (size_t)(jh * JSPAN + srow) * DMODEL + h * HD + sg;
    const unsigned short* Vg = Vt + (size_t)(h * HD + srow) * NSEQ + jh * JSPAN + sg;

    // prefetch tile 0 into regs
    ushort8_t kr0 = *reinterpret_cast<const ushort8_t*>(Kg);
    ushort8_t kr1 = *reinterpret_cast<const ushort8_t*>(Kg + 8);
    ushort8_t vr0 = *reinterpret_cast<const ushort8_t*>(Vg);
    ushort8_t vr1 = *reinterpret_cast<const ushort8_t*>(Vg + 8);

    const int ntb = JSPAN / 64;
    for (int tb = 0; tb < ntb; ++tb) {
        __syncthreads();   // prev tile consumed; (tb=0) kcs visible
        *reinterpret_cast<ushort8_t*>(&Khs[srow * 64 + sw0]) = kr0;
        *reinterpret_cast<ushort8_t*>(&Khs[srow * 64 + sw1]) = kr1;
        *reinterpret_cast<ushort8_t*>(&Vts[srow * 64 + sw0]) = vr0;
        *reinterpret_cast<ushort8_t*>(&Vts[srow * 64 + sw1]) = vr1;
        if (tb + 1 < ntb) {   // T14: next-tile loads overlap with compute
            const unsigned short* kn_ = Kg + (size_t)(tb + 1) * 64 * DMODEL;
            const unsigned short* vn_ = Vg + (tb + 1) * 64;
            kr0 = *reinterpret_cast<const ushort8_t*>(kn_);
            kr1 = *reinterpret_cast<const ushort8_t*>(kn_ + 8);
            vr0 = *reinterpret_cast<const ushort8_t*>(vn_);
            vr1 = *reinterpret_cast<const ushort8_t*>(vn_ + 8);
        }
        __syncthreads();

        // ---- S tiles + distance -> w -> P (swizzled wave-private LDS) ----
#pragma unroll
        for (int jt = 0; jt < 4; ++jt) {
            f32x4 sac = (f32x4){0.f, 0.f, 0.f, 0.f};
#pragma unroll
            for (int dc = 0; dc < 2; ++dc) {
                const bf16x8 kb = *reinterpret_cast<const bf16x8*>(
                    &Khs[(jt * 16 + r) * 64 + ((dc * 4 + g) ^ (r & 7)) * 8]);
                sac = __builtin_amdgcn_mfma_f32_16x16x32_bf16(qf[dc], kb, sac, 0, 0, 0);
            }
            const float2 kc = kcs[tb * 64 + jt * 16 + r];
#pragma unroll
            for (int rg = 0; rg < 4; ++rg) {
                const float dsq = fmaf(-2.f, sac[rg], qn_r[rg] + kc.x);
                const float ca  = fmaxf(fmaf(dsq, c2q[rg] * kc.y, 1.f), 1.0f);
                const float s2  = fmaf(ca, ca, -1.f);
                const float wj  = ca - __builtin_amdgcn_sqrtf(s2);
                l_acc[rg] += wj;
                const int qrow = g * 4 + rg;
                Pw[qrow * 64 +
                   ((2 * jt + (r >> 3)) ^ (qrow & 7)) * 8 + (r & 7)] = f2bf(wj);
            }
        }
        // Pw is wave-private: within-wave ds ordering suffices

        // ---- PV: O[q][d] += P . V ----
#pragma unroll
        for (int kc2 = 0; kc2 < 2; ++kc2) {
            const bf16x8 pa = *reinterpret_cast<const bf16x8*>(
                &Pw[r * 64 + ((kc2 * 4 + g) ^ (r & 7)) * 8]);
#pragma unroll
            for (int nt = 0; nt < 4; ++nt) {
                const bf16x8 vb = *reinterpret_cast<const bf16x8*>(
                    &Vts[(nt * 16 + r) * 64 + ((kc2 * 4 + g) ^ (r & 7)) * 8]);
                oacc[nt] = __builtin_amdgcn_mfma_f32_16x16x32_bf16(pa, vb, oacc[nt], 0, 0, 0);
            }
        }
    }

    // ---- l reduce over the 16 r-lanes ----
#pragma unroll
    for (int rg = 0; rg < 4; ++rg) {
        l_acc[rg] += __shfl_xor(l_acc[rg], 1, 64);
        l_acc[rg] += __shfl_xor(l_acc[rg], 2, 64);
        l_acc[rg] += __shfl_xor(l_acc[rg], 4, 64);
        l_acc[rg] += __shfl_xor(l_acc[rg], 8, 64);
    }

    // ---- write partials ----
    float* Op = Opart + (size_t)jh * NSEQ * DMODEL;
#pragma unroll
    for (int nt = 0; nt < 4; ++nt)
#pragma unroll
        for (int rg = 0; rg < 4; ++rg)
            Op[(size_t)(qb + g * 4 + rg) * DMODEL + h * HD + nt * 16 + r] =
                oacc[nt][rg];
    if (r == 0) {
#pragma unroll
        for (int rg = 0; rg < 4; ++rg)
            lpart[(jh * NHEADS + h) * NSEQ + qb + g * 4 + rg] = l_acc[rg];
    }
}

// ---------------------------------------------------------------------------
// Merge j-split partials: Ob = bf16((O0+O1) / (l0+l1)).
// ---------------------------------------------------------------------------
__global__ __launch_bounds__(256) void merge_kernel(
    const float* __restrict__ Opart, const float* __restrict__ lpart,
    unsigned short* __restrict__ Ob)
{
    const size_t i8 = ((size_t)blockIdx.x * 256 + threadIdx.x) * 8;
    if (i8 >= (size_t)NSEQ * DMODEL) return;
    const int n  = (int)(i8 >> 10);
    const int dm = (int)(i8 & 1023);
    const int h  = dm >> 6;
    const float li = 1.0f / (lpart[h * NSEQ + n] +
                             lpart[(NHEADS + h) * NSEQ + n]);
    const float* O0 = Opart + i8;
    const float* O1 = Opart + (size_t)NSEQ * DMODEL + i8;
    ushort8_t o;
#pragma unroll
    for (int c = 0; c < 2; ++c) {
        const float4 a = *reinterpret_cast<const float4*>(O0 + c * 4);
        const float4 b = *reinterpret_cast<const float4*>(O1 + c * 4);
        o[c * 4 + 0] = f2bf((a.x + b.x) * li);
        o[c * 4 + 1] = f2bf((a.y + b.y) * li);
        o[c * 4 + 2] = f2bf((a.z + b.z) * li);
        o[c * 4 + 3] = f2bf((a.w + b.w) * li);
    }
    *reinterpret_cast<ushort8_t*>(Ob + i8) = o;
}

// ---------------------------------------------------------------------------
extern "C" void kernel_launch(void* const* d_in, const int* in_sizes, int n_in,
                              void* d_out, int out_size, void* d_ws, size_t ws_size,
                              hipStream_t stream)
{
    const float* x  = (const float*)d_in[0];
    const float* Wq = (const float*)d_in[1];
    const float* Wk = (const float*)d_in[2];
    const float* Wv = (const float*)d_in[3];
    const float* Wo = (const float*)d_in[4];
    float* out = (float*)d_out;

    char* ws = (char*)d_ws;
    const size_t MB = 1048576;
    unsigned short* xb   = (unsigned short*)(ws);             // 4MB (-> Ob)
    unsigned short* Wb   = (unsigned short*)(ws + 4  * MB);   // 6MB
    unsigned short* Wob  = (unsigned short*)(ws + 10 * MB);   // 2MB
    unsigned short* Qbuf = (unsigned short*)(ws + 12 * MB);   // 4MB
    unsigned short* Kbuf = (unsigned short*)(ws + 16 * MB);   // 4MB
    unsigned short* Vt   = (unsigned short*)(ws + 20 * MB);   // 4MB
    float2*         qnc2 = (float2*)(ws + 24 * MB);           // 256KB
    float2*         knck = (float2*)(ws + 24 * MB + 262144);  // 256KB
    float*          Opart= (float*)(ws + 25 * MB);            // 16MB
    float*          lpart= (float*)(ws + 41 * MB);            // 256KB
    unsigned short* Ob   = xb;   // xb dead after QKV GEMM

    const dim3 blk(256);

    // 1. fp32 -> bf16 conversions
    convert_inputs<<<3072, blk, 0, stream>>>(x, Wq, Wk, Wv, Wo, xb, Wb, Wob);

    // 2. fused QKV projection + norms + V-transpose in epilogue  [768 blocks]
    gemm_bt_bf16<1><<<dim3(NSEQ / 128, 3072 / 64), blk, 0, stream>>>(
        xb, Wb, nullptr, Qbuf, qnc2, Kbuf, knck, Vt);

    // 3. attention partials (j-split x2, T14 pipeline)  [1024 blocks]
    hyp_attn_v8<<<dim3(NSEQ / 64, NHEADS, NJH), blk, 0, stream>>>(
        Qbuf, Kbuf, Vt, qnc2, knck, Opart, lpart);

    // 4. merge partials -> Ob (bf16)
    merge_kernel<<<(NSEQ * DMODEL / 8 + 255) / 256, blk, 0, stream>>>(
        Opart, lpart, Ob);

    // 5. output projection  [256 blocks]
    gemm_bt_bf16<0><<<dim3(NSEQ / 128, DMODEL / 64), blk, 0, stream>>>(
        Ob, Wob, out, nullptr, nullptr, nullptr, nullptr, nullptr);
}